// Round 8
// baseline (659.444 us; speedup 1.0000x reference)
//
#include <hip/hip_runtime.h>
#include <hip/hip_fp8.h>
#include <stdint.h>

// ---------------------------------------------------------------- constants
#define NB     8192     // batch
#define NF     256      // features
#define NHALF  128      // F/2
#define NHID   512      // hidden = 2F
#define NLAY   4        // coupling layers
#define NK     32768    // codebook size

#define SX     (1.0f / 16.0f)    // x scale for fp8 (|x|<=474/16=30 < 448)
#define SP     (256.0f)          // p scale for fp8 (Glorot +-0.0135*256=3.46)

typedef __attribute__((ext_vector_type(8))) short bf16x8;   // 8 bf16 = 4 VGPR
typedef __attribute__((ext_vector_type(4))) float f32x4;
typedef __attribute__((ext_vector_type(2))) long i64x2;     // 16 B = 2 fp8 frags

static __device__ __forceinline__ unsigned short f2bf(float f) {
  union { float f; unsigned int u; } v; v.f = f;
  return (unsigned short)((v.u + 0x7FFFu + ((v.u >> 16) & 1u)) >> 16);  // RNE
}
static __device__ __forceinline__ float bf2f(unsigned short u) {
  union { unsigned int u; float f; } v; v.u = ((unsigned int)u) << 16; return v.f;
}
static __device__ __forceinline__ unsigned char f2fp8(float f) {
  __hip_fp8_e4m3 q(f);                       // OCP e4m3fn, RNE + saturate
  return (unsigned char)q.__x;
}
static __device__ __forceinline__ float fp82f(unsigned char b) {
  __hip_fp8_e4m3 q; q.__x = b; return (float)q;
}
// permuted byte index inside a 256-k row: k' = q*64 + kc*8 + j for
// k = kc*32 + q*8 + j  -> one 16B load at q*64+kc2*16 = two K=32 fp8 frags
static __device__ __forceinline__ int kperm(int k) {
  return ((k >> 3) & 3) * 64 + ((k >> 5) << 3) + (k & 7);
}

// async global->LDS, 16B per lane; LDS dest = wave-uniform base + lane*16
static __device__ __forceinline__ void load_lds16(const void* g, void* l) {
  __builtin_amdgcn_global_load_lds(
      (const __attribute__((address_space(1))) unsigned int*)g,
      (__attribute__((address_space(3))) unsigned int*)l, 16, 0, 0);
}

// pack (score, idx) so u64 max == argmax with smallest-index tiebreak
static __device__ __forceinline__ unsigned long long packsi(float v, int idx) {
  unsigned int b = __float_as_uint(v);
  b = (b & 0x80000000u) ? ~b : (b | 0x80000000u);   // order-preserving map
  return ((unsigned long long)b << 32) | (unsigned int)(~(unsigned int)idx);
}

static __device__ __forceinline__ float fast_tanh(float x) {
  const float xc = fminf(fmaxf(x, -15.f), 15.f);
  const float e2 = __expf(2.f * xc);
  return 1.f - 2.f / (e2 + 1.f);
}

// LDS tile address: [kseg][row][64 shorts], 3-bit XOR chunk swizzle.
// Proven 0-conflict (R2/R4/R6) for ds_read_b128 with 16 lanes on rows.
static __device__ __forceinline__ int swadr(int kseg, int nrows, int row, int kin) {
  return (kseg * nrows + row) * 64 + (((kin >> 3) ^ (row & 7)) * 8) + (kin & 7);
}

// ---------------------------------------------------------------- fused flow (ALL 4 layers)
// BARRIER-FREE: one 64-thread block = one wave = 16 batch rows end-to-end.
// R7 post-mortem: __syncthreads forces vmcnt(0) drain of any in-flight
// global_load_lds (compiler-emitted before s_barrier) -> per-segment DMA
// serialization. Here every dependency is wave-local: weights are read as
// B-fragments DIRECTLY from global (all waves read the same 1.5 MB -> L1/L2
// cached), x-state + h in wave-private LDS ordered by lgkmcnt only.
__global__ __launch_bounds__(64)
void flow_all(const float* __restrict__ in,
              const unsigned short* __restrict__ W1T,   // [L][512][128]
              const unsigned short* __restrict__ W2I,   // [L][256][512] s/t interleaved
              const float* __restrict__ b1A,
              const float* __restrict__ bsA,
              const float* __restrict__ btA,
              float* __restrict__ xout,
              unsigned char* __restrict__ xf8,          // [NB][256] permuted fp8(x*SX)
              float* __restrict__ jac)
{
  __shared__ __align__(16) unsigned short Xb[2][16 * 128];   // 8 KB x-state
  __shared__ __align__(16) unsigned short Hs[16 * 64];       // 2 KB h chunk
  const int lane = threadIdx.x & 63;
  const int q = lane >> 4, c = lane & 15;
  const int m0 = blockIdx.x * 16;

  // ---- init x-state: Xb[0]=bf16(in[:, :128]) (xa0), Xb[1]=bf16(in[:,128:]) (xb0)
#pragma unroll
  for (int v = 0; v < 16; v++) {
    const int t4 = lane + v * 64;            // 1024 float4s = 16 rows x 64
    const int row = t4 >> 6, f4 = t4 & 63;
    const float4 d = *(const float4*)(in + (size_t)(m0 + row) * NF + f4 * 4);
    unsigned short* dst = Xb[f4 >> 5];
    const int feat = (f4 & 31) * 4;
    const float vals[4] = {d.x, d.y, d.z, d.w};
#pragma unroll
    for (int u = 0; u < 4; u++) {
      const int fe = feat + u;
      dst[swadr(fe >> 6, 16, row, fe & 63)] = f2bf(vals[u]);
    }
  }

  float jr[4] = {0.f, 0.f, 0.f, 0.f};
  const f32x4 z = {0.f, 0.f, 0.f, 0.f};

  for (int l = 0; l < NLAY; l++) {
    const unsigned short* W1l = W1T + (size_t)l * NHID * NHALF;
    const unsigned short* W2l = W2I + (size_t)l * NF * NHID;
    const float* bsl = bsA + l * NHALF;
    const float* btl = btA + l * NHALF;
    unsigned short* XA = Xb[l & 1];
    unsigned short* XB = Xb[1 - (l & 1)];

    // GEMM1 A-fragments from XA (wave-private LDS; lgkmcnt auto-ordered)
    bf16x8 af1[4];
#pragma unroll
    for (int kw = 0; kw < 4; kw++) {
      const int kch = kw * 4 + q;
      af1[kw] = *(const bf16x8*)(XA + ((kch >> 3) * 16 + c) * 64 +
                                 (((kch & 7) ^ (c & 7)) * 8));
    }

    f32x4 acc2[16];
#pragma unroll
    for (int j = 0; j < 16; j++) acc2[j] = z;

    for (int ch8 = 0; ch8 < 8; ch8++) {     // 64 h-cols per chunk
      // ---- GEMM1: 4 col-tiles of 16, B-frags straight from global (L1-hot)
#pragma unroll
      for (int j = 0; j < 4; j++) {
        const int col = ch8 * 64 + j * 16 + c;
        f32x4 a = z;
#pragma unroll
        for (int kw = 0; kw < 4; kw++) {
          const bf16x8 bf = *(const bf16x8*)(W1l + (size_t)col * NHALF + kw * 32 + q * 8);
          a = __builtin_amdgcn_mfma_f32_16x16x32_bf16(af1[kw], bf, a, 0, 0, 0);
        }
        const int hc = j * 16 + c;          // 0..63 within chunk
        const float bb = b1A[l * NHID + ch8 * 64 + hc];
#pragma unroll
        for (int r = 0; r < 4; r++) {
          float v = a[r] + bb;
          v = v > 0.f ? v : 0.f;
          Hs[swadr(0, 16, 4 * q + r, hc)] = f2bf(v);
        }
      }
      // ---- GEMM2: K=64 slice; A-frags from Hs (wave-local, lgkmcnt auto)
      bf16x8 afh[2];
#pragma unroll
      for (int kc = 0; kc < 2; kc++) {
        const int kch = kc * 4 + q;
        afh[kc] = *(const bf16x8*)(Hs + c * 64 + ((kch ^ (c & 7)) * 8));
      }
#pragma unroll
      for (int j2 = 0; j2 < 16; j2++) {
        const int col = j2 * 16 + c;
#pragma unroll
        for (int kc = 0; kc < 2; kc++) {
          const bf16x8 bf = *(const bf16x8*)(W2l + (size_t)col * NHID + ch8 * 64 + kc * 32 + q * 8);
          acc2[j2] = __builtin_amdgcn_mfma_f32_16x16x32_bf16(afh[kc], bf, acc2[j2], 0, 0, 0);
        }
      }
    }

    // ---- coupling epilogue (even col=s, odd col=t); all wave-local
    const int parity = c & 1;
    const int lastl = (l == NLAY - 1);
#pragma unroll
    for (int j2 = 0; j2 < 16; j2++) {
      const int col = j2 * 16 + c;
#pragma unroll
      for (int r = 0; r < 4; r++) {
        const float val = acc2[j2][r];
        const float oth = __shfl_xor(val, 1);   // all lanes participate
        if (!parity) {
          const int feat = col >> 1;
          float sv = val + bsl[feat];
          if (!lastl) sv = fast_tanh(sv);
          const float t = oth + btl[feat];
          const int row = 4 * q + r;
          const int xaddr = swadr(feat >> 6, 16, row, feat & 63);
          const float xb = bf2f(XB[xaddr]);
          const float yb = xb * __expf(sv) + t;
          jr[r] += sv;
          XB[xaddr] = f2bf(yb);                 // in-place: same owner thread
          if (l >= 2) {
            const int k = lastl ? feat : (NHALF + feat);
            const size_t grow = (size_t)(m0 + row) * NF;
            xout[grow + k] = yb;
            xf8[(size_t)(m0 + row) * 256 + kperm(k)] = f2fp8(yb * SX);
          }
        }
      }
    }
  }

  // jac: reduce 16 c-lanes in-wave; each (q,r) row owned by this wave only
#pragma unroll
  for (int r = 0; r < 4; r++) {
    float v = jr[r];
    v += __shfl_xor(v, 1); v += __shfl_xor(v, 2);
    v += __shfl_xor(v, 4); v += __shfl_xor(v, 8);
    if (c == 0) jac[m0 + 4 * q + r] = v;
  }
}

// ---------------------------------------------------------------- VQ argmax (fp8)
// Grid 1024: slice = bx & 31 (XCD-pinned, 1 MB P8 per XCD -> L2-resident),
// m-group = bx >> 5 (256 rows). 4 blocks/CU (16 waves: launch_bounds(256,4),
// 112 VGPR x 4 = 448 <= 512) so LDS reads + argmax VALU co-schedule under
// other waves' MFMA (m114). 64 register-resident fp8 X rows per wave.
__global__ __launch_bounds__(256, 4)
void vq_argmax(const unsigned char* __restrict__ X8,   // [NB][256] permuted fp8
               const unsigned char* __restrict__ P8,   // [NK][256] permuted fp8
               const float* __restrict__ nbh,          // [NK] scaled 0.5||p||^2
               unsigned long long* __restrict__ gbest) // [NB] packed
{
  __shared__ __align__(16) unsigned char Bs[64 * 256];  // 16 KB
  const int tid = threadIdx.x;
  const int lane = tid & 63, wave = tid >> 6;
  const int y = blockIdx.x & 31;
  const int m0 = (blockIdx.x >> 5) * 256;
  const int q = lane >> 4, c = lane & 15;
  const int mw = m0 + wave * 64;

  long af[4][8];
#pragma unroll
  for (int i = 0; i < 4; i++) {
    const unsigned char* xr = X8 + (size_t)(mw + 16 * i + c) * 256 + q * 64;
#pragma unroll
    for (int kc2 = 0; kc2 < 4; kc2++) {
      const i64x2 v = *(const i64x2*)(xr + kc2 * 16);
      af[i][2 * kc2] = v.x; af[i][2 * kc2 + 1] = v.y;
    }
  }

  float bestv[16];
  int besti[16];
#pragma unroll
  for (int t = 0; t < 16; t++) { bestv[t] = -1e30f; besti[t] = 0; }

  for (int nt = 0; nt < 16; nt++) {
    const int n0 = y * 1024 + nt * 64;
    if (nt) __syncthreads();
    // stage 64 codes x 256 B: slot (row,gslot) holds src chunk gslot^(row&15)
#pragma unroll
    for (int u = 0; u < 4; u++) {
      const int chb = (u * 4 + wave) * 64;
      const int ch = chb + lane;
      const int row = ch >> 4, gslot = ch & 15;
      load_lds16(P8 + (size_t)(n0 + row) * 256 + (gslot ^ (row & 15)) * 16,
                 Bs + chb * 16);
    }
    __syncthreads();

    const f32x4 z = {0.f, 0.f, 0.f, 0.f};
    f32x4 acc[4][4];
#pragma unroll
    for (int i = 0; i < 4; i++)
#pragma unroll
      for (int j = 0; j < 4; j++) acc[i][j] = z;

#pragma unroll
    for (int kc2 = 0; kc2 < 4; kc2++) {
      const int g = q * 4 + kc2;
#pragma unroll
      for (int j = 0; j < 4; j++) {
        const int rb = 16 * j + c;
        const i64x2 b2 = *(const i64x2*)(Bs + rb * 256 + ((g ^ (rb & 15)) * 16));
#pragma unroll
        for (int i = 0; i < 4; i++) {
          acc[i][j] = __builtin_amdgcn_mfma_f32_16x16x32_fp8_fp8(af[i][2 * kc2],     b2.x, acc[i][j], 0, 0, 0);
          acc[i][j] = __builtin_amdgcn_mfma_f32_16x16x32_fp8_fp8(af[i][2 * kc2 + 1], b2.y, acc[i][j], 0, 0, 0);
        }
      }
    }

    // lane-local running argmax (ascending col + strict > = lowest-index ties)
#pragma unroll
    for (int j = 0; j < 4; j++) {
      const int col = n0 + 16 * j + c;
      const float nb = nbh[col];
#pragma unroll
      for (int i = 0; i < 4; i++)
#pragma unroll
        for (int r = 0; r < 4; r++) {
          const float sc = acc[i][j][r] - nb;
          const int t = i * 4 + r;
          if (sc > bestv[t]) { bestv[t] = sc; besti[t] = col; }
        }
    }
  }

  // reduce across 16 c-lanes per slot; rows unique per (wave, i, q, r)
#pragma unroll
  for (int t = 0; t < 16; t++) {
    float lv = bestv[t]; int li = besti[t];
#pragma unroll
    for (int mk = 8; mk >= 1; mk >>= 1) {
      const float ov = __shfl_xor(lv, mk);
      const int oi = __shfl_xor(li, mk);
      if (ov > lv || (ov == lv && oi < li)) { lv = ov; li = oi; }
    }
    if (c == 0) {
      const int row = mw + 16 * (t >> 2) + q * 4 + (t & 3);
      atomicMax(&gbest[row], packsi(lv, li));
    }
  }
}

// ---------------------------------------------------------------- fused prep
// bx [0,2048): prior -> permuted fp8 (scale SP) + scaled nbh | [2048,2112):
// W1 transpose | [2112,2240): Ws/Wt -> W2I interleave | [2240,2272): init
__global__ void prep_all(const float* __restrict__ W1,
                         const float* __restrict__ Ws,
                         const float* __restrict__ Wt,
                         const float* __restrict__ prior,
                         unsigned short* __restrict__ W1T,
                         unsigned short* __restrict__ W2I,
                         unsigned char* __restrict__ p8,
                         float* __restrict__ nbh,
                         unsigned long long* __restrict__ gbest,
                         float* __restrict__ accum)
{
  __shared__ float ts[64 * 65];
  const int bx = blockIdx.x;
  const int tid = threadIdx.x;
  if (bx < 2048) {
    const int k = bx * 16 + (tid >> 4);      // code index
    const int l16 = tid & 15;
    float s = 0.f;
#pragma unroll
    for (int v = 0; v < 4; v++) {
      const int off = (v * 16 + l16) * 4;    // k-offset, multiple of 4
      const float4 d = *(const float4*)(prior + (size_t)k * NF + off);
      uchar4 o;
      o.x = f2fp8(d.x * SP); o.y = f2fp8(d.y * SP);
      o.z = f2fp8(d.z * SP); o.w = f2fp8(d.w * SP);
      *(uchar4*)(p8 + (size_t)k * 256 + kperm(off)) = o;   // 4 consec bytes
      const float q0 = fp82f(o.x), q1 = fp82f(o.y), q2 = fp82f(o.z), q3 = fp82f(o.w);
      s += q0 * q0 + q1 * q1 + q2 * q2 + q3 * q3;
    }
#pragma unroll
    for (int mk = 8; mk >= 1; mk >>= 1) s += __shfl_xor(s, mk);
    if (l16 == 0) nbh[k] = 0.5f * s * (SX / SP);   // consistent scaled domain
  } else if (bx < 2112) {
    const int job = bx - 2048;
    const int l = job >> 4, t = job & 15;
    const int k0 = (t >> 3) * 64, n0 = (t & 7) * 64;
    const float* src = W1 + (size_t)l * NHALF * NHID;
#pragma unroll
    for (int v = 0; v < 16; v++) {
      const int e = tid + v * 256;
      const int kk = e >> 6, nn = e & 63;
      ts[kk * 65 + nn] = src[(size_t)(k0 + kk) * NHID + n0 + nn];
    }
    __syncthreads();
    unsigned short* dst = W1T + (size_t)l * NHID * NHALF;
#pragma unroll
    for (int v = 0; v < 16; v++) {
      const int e = tid + v * 256;
      const int nn = e >> 6, kk = e & 63;
      dst[(size_t)(n0 + nn) * NHALF + k0 + kk] = f2bf(ts[kk * 65 + nn]);
    }
  } else if (bx < 2240) {
    const int job = bx - 2112;
    const int l = job >> 5, rem = job & 31;
    const int b = rem >> 4;
    const int k0 = ((rem >> 1) & 7) * 64;
    const int f0 = (rem & 1) * 64;
    const float* src = (b ? Wt : Ws) + (size_t)l * NHID * NHALF;
#pragma unroll
    for (int v = 0; v < 16; v++) {
      const int e = tid + v * 256;
      const int kk = e >> 6, nn = e & 63;
      ts[kk * 65 + nn] = src[(size_t)(k0 + kk) * NHALF + f0 + nn];
    }
    __syncthreads();
#pragma unroll
    for (int v = 0; v < 16; v++) {
      const int e = tid + v * 256;
      const int nn = e >> 6, kk = e & 63;
      W2I[((size_t)l * NF + 2 * (f0 + nn) + b) * NHID + k0 + kk] = f2bf(ts[kk * 65 + nn]);
    }
  } else {
    const int idx = (bx - 2240) * 256 + tid;
    if (idx < NB) gbest[idx] = 0ull;
    if (idx < 2) accum[idx] = 0.f;
  }
}

// ---------------------------------------------------------------- VQ finalize
__global__ void vq_finalize(const float* __restrict__ X,      // d_out x, fp32
                            const float* __restrict__ prior,
                            const unsigned long long* __restrict__ gbest,
                            const float* __restrict__ jac,
                            float* __restrict__ accum)        // [0]=dist,[1]=jac
{
  const int wave = threadIdx.x >> 6, lane = threadIdx.x & 63;
  const int gw = blockIdx.x * 4 + wave;        // 1024 waves, 8 rows each
  float accd = 0.f, accj = 0.f;
  for (int r = 0; r < 8; r++) {
    const int row = gw * 8 + r;
    const unsigned int idx = ~(unsigned int)(gbest[row]);   // low 32 bits = ~idx
    const float* x = X + (size_t)row * NF;
    const float* p = prior + (size_t)idx * NF;
#pragma unroll
    for (int u = 0; u < 4; u++) {
      const int d = lane + u * 64;
      const float df = x[d] - p[d];
      accd += df * df;
    }
    if (lane == 0) accj += jac[row];
  }
#pragma unroll
  for (int mk = 32; mk >= 1; mk >>= 1) {
    accd += __shfl_xor(accd, mk);
    accj += __shfl_xor(accj, mk);
  }
  __shared__ float sd[4], sj[4];
  if (lane == 0) { sd[wave] = accd; sj[wave] = accj; }
  __syncthreads();
  if (threadIdx.x == 0) {
    atomicAdd(&accum[0], sd[0] + sd[1] + sd[2] + sd[3]);
    atomicAdd(&accum[1], sj[0] + sj[1] + sj[2] + sj[3]);
  }
}

__global__ void finalize_loss(const float* __restrict__ acc, float* __restrict__ loss) {
  if (threadIdx.x == 0 && blockIdx.x == 0)
    loss[0] = 1.25f * (0.5f * acc[0] / (float)NB) - acc[1] / (float)NB;
}

// ---------------------------------------------------------------- launch
extern "C" void kernel_launch(void* const* d_in, const int* in_sizes, int n_in,
                              void* d_out, int out_size, void* d_ws, size_t ws_size,
                              hipStream_t stream)
{
  (void)in_sizes; (void)n_in; (void)out_size; (void)ws_size;
  const float* inputs = (const float*)d_in[0];
  const float* W1 = (const float*)d_in[1];
  const float* b1 = (const float*)d_in[2];
  const float* Ws = (const float*)d_in[3];
  const float* bs = (const float*)d_in[4];
  const float* Wt = (const float*)d_in[5];
  const float* bt = (const float*)d_in[6];
  const float* prior = (const float*)d_in[7];

  char* p = (char*)d_ws;
  auto alloc = [&](size_t bytes) { char* r = p; p += (bytes + 255) & ~(size_t)255; return r; };
  unsigned short* W1T  = (unsigned short*)alloc((size_t)NLAY * NHID * NHALF * 2);
  unsigned short* W2I  = (unsigned short*)alloc((size_t)NLAY * NF * NHID * 2);
  unsigned char* P8    = (unsigned char*)alloc((size_t)NK * 256);
  float* NBH           = (float*)alloc((size_t)NK * 4);
  unsigned char* XF8   = (unsigned char*)alloc((size_t)NB * 256);
  float* JAC           = (float*)alloc((size_t)NB * 4);
  unsigned long long* GBEST = (unsigned long long*)alloc((size_t)NB * 8);
  float* ACC           = (float*)alloc(256);

  float* xout = (float*)d_out;                 // [NB][NF]
  float* loss = xout + (size_t)NB * NF;        // scalar

  prep_all<<<dim3(2272), 256, 0, stream>>>(
      W1, Ws, Wt, prior, W1T, W2I, P8, NBH, GBEST, ACC);

  flow_all<<<dim3(NB / 16), 64, 0, stream>>>(
      inputs, W1T, W2I, b1, bs, bt, xout, XF8, JAC);

  vq_argmax<<<dim3(32 * 32), 256, 0, stream>>>(XF8, P8, NBH, GBEST);
  vq_finalize<<<dim3(256), 256, 0, stream>>>(xout, prior, GBEST, JAC, ACC);
  finalize_loss<<<1, 1, 0, stream>>>(ACC, loss);
}

// Round 9
// 509.469 us; speedup vs baseline: 1.2944x; 1.2944x over previous
//
#include <hip/hip_runtime.h>
#include <hip/hip_fp8.h>
#include <stdint.h>

// ---------------------------------------------------------------- constants
#define NB     8192     // batch
#define NF     256      // features
#define NHALF  128      // F/2
#define NHID   512      // hidden = 2F
#define NLAY   4        // coupling layers
#define NK     32768    // codebook size

#define SX     (1.0f / 16.0f)    // x scale for fp8 (|x|<=474/16=30 < 448)
#define SP     (256.0f)          // p scale for fp8 (Glorot +-0.0135*256=3.46)

typedef __attribute__((ext_vector_type(8))) short bf16x8;   // 8 bf16 = 4 VGPR
typedef __attribute__((ext_vector_type(4))) float f32x4;
typedef __attribute__((ext_vector_type(2))) long i64x2;     // 16 B = 2 fp8 frags

static __device__ __forceinline__ unsigned short f2bf(float f) {
  union { float f; unsigned int u; } v; v.f = f;
  return (unsigned short)((v.u + 0x7FFFu + ((v.u >> 16) & 1u)) >> 16);  // RNE
}
static __device__ __forceinline__ float bf2f(unsigned short u) {
  union { unsigned int u; float f; } v; v.u = ((unsigned int)u) << 16; return v.f;
}
static __device__ __forceinline__ unsigned char f2fp8(float f) {
  __hip_fp8_e4m3 q(f);                       // OCP e4m3fn, RNE + saturate
  return (unsigned char)q.__x;
}
static __device__ __forceinline__ float fp82f(unsigned char b) {
  __hip_fp8_e4m3 q; q.__x = b; return (float)q;
}
// permuted byte index inside a 256-k row: k' = q*64 + kc*8 + j for
// k = kc*32 + q*8 + j  -> one 16B load at q*64+kc2*16 = two K=32 fp8 frags
static __device__ __forceinline__ int kperm(int k) {
  return ((k >> 3) & 3) * 64 + ((k >> 5) << 3) + (k & 7);
}

// async global->LDS, 16B per lane; LDS dest = wave-uniform base + lane*16
static __device__ __forceinline__ void load_lds16(const void* g, void* l) {
  __builtin_amdgcn_global_load_lds(
      (const __attribute__((address_space(1))) unsigned int*)g,
      (__attribute__((address_space(3))) unsigned int*)l, 16, 0, 0);
}

// pack (score, idx) so u64 max == argmax with smallest-index tiebreak
static __device__ __forceinline__ unsigned long long packsi(float v, int idx) {
  unsigned int b = __float_as_uint(v);
  b = (b & 0x80000000u) ? ~b : (b | 0x80000000u);   // order-preserving map
  return ((unsigned long long)b << 32) | (unsigned int)(~(unsigned int)idx);
}

static __device__ __forceinline__ float fast_tanh(float x) {
  const float xc = fminf(fmaxf(x, -15.f), 15.f);
  const float e2 = __expf(2.f * xc);
  return 1.f - 2.f / (e2 + 1.f);
}

// LDS tile address: [kseg][row][64 shorts], 3-bit XOR chunk swizzle.
// Proven 0-conflict (R2/R4/R6) for ds_read_b128 with 16 lanes on rows.
static __device__ __forceinline__ int swadr(int kseg, int nrows, int row, int kin) {
  return (kseg * nrows + row) * 64 + (((kin >> 3) ^ (row & 7)) * 8) + (kin & 7);
}

// ---------------------------------------------------------------- fused flow (ALL 4 layers)
// R6-proven barrier structure, merged stages: per nc-chunk stage W1 (32 KB)
// then the FULL W2 K-chunk (64 KB) in one DMA burst -> 17 barriers/layer
// (vs 96 total small ones). One block = 16 rows, grid 512, LDS 76 KB ->
// 2 blocks/CU so one block's compute covers the other's barrier drains.
// (R8's barrier-free variant regressed: per-wave weight reads, 2 waves/CU.)
__global__ __launch_bounds__(256, 2)
void flow_all(const float* __restrict__ in,
              const unsigned short* __restrict__ W1T,   // [L][512][128]
              const unsigned short* __restrict__ W2I,   // [L][256][512] s/t interleaved
              const float* __restrict__ b1A,
              const float* __restrict__ bsA,
              const float* __restrict__ btA,
              float* __restrict__ xout,
              unsigned char* __restrict__ xf8,          // [NB][256] permuted fp8(x*SX)
              float* __restrict__ jac)
{
  __shared__ __align__(16) unsigned short Xb[2][16 * 128];   //  8 KB x-state
  __shared__ __align__(16) unsigned short Hs[2 * 16 * 64];   //  4 KB h chunk
  __shared__ __align__(16) unsigned short Bs[32768];         // 64 KB W staging
  __shared__ float jlds[3][16];
  const int tid = threadIdx.x;
  const int lane = tid & 63, wave = tid >> 6;
  const int q = lane >> 4, c = lane & 15;
  const int m0 = blockIdx.x * 16;

  // ---- init x-state: Xb[0]=bf16(in[:, :128]) (xa0), Xb[1]=bf16(in[:,128:]) (xb0)
#pragma unroll
  for (int v = 0; v < 4; v++) {
    const int t4 = tid + v * 256;            // 1024 float4s = 16 rows x 64
    const int row = t4 >> 6, f4 = t4 & 63;
    const float4 d = *(const float4*)(in + (size_t)(m0 + row) * NF + f4 * 4);
    unsigned short* dst = Xb[f4 >> 5];
    const int feat = (f4 & 31) * 4;
    const float vals[4] = {d.x, d.y, d.z, d.w};
#pragma unroll
    for (int u = 0; u < 4; u++) {
      const int fe = feat + u;
      dst[swadr(fe >> 6, 16, row, fe & 63)] = f2bf(vals[u]);
    }
  }

  float jr[4] = {0.f, 0.f, 0.f, 0.f};
  const f32x4 z = {0.f, 0.f, 0.f, 0.f};

  for (int l = 0; l < NLAY; l++) {
    __syncthreads();                          // x-state settled; Bs free
    const unsigned short* W1l = W1T + (size_t)l * NHID * NHALF;
    const unsigned short* W2l = W2I + (size_t)l * NF * NHID;
    const float* bsl = bsA + l * NHALF;
    const float* btl = btA + l * NHALF;
    unsigned short* XA = Xb[l & 1];
    unsigned short* XB = Xb[1 - (l & 1)];

    // GEMM1 A-fragments from XA (row = c, k-chunk = kw*4+q)
    bf16x8 af1[4];
#pragma unroll
    for (int kw = 0; kw < 4; kw++) {
      const int kch = kw * 4 + q;
      af1[kw] = *(const bf16x8*)(XA + ((kch >> 3) * 16 + c) * 64 +
                                 (((kch & 7) ^ (c & 7)) * 8));
    }

    f32x4 acc2[4];
#pragma unroll
    for (int j = 0; j < 4; j++) acc2[j] = z;

    for (int nc = 0; nc < 4; nc++) {
      // ---- stage W1[nc*128 .. +128][0..128] as [kseg2][128][64] (32 KB)
#pragma unroll
      for (int u = 0; u < 8; u++) {
        const int chb = (wave * 8 + u) * 64;
        const int ch = chb + lane;
        const int kseg = ch >> 10, cs = ch & 1023;
        const int row = cs >> 3, cc = (cs & 7) ^ (row & 7);
        load_lds16(W1l + (size_t)(nc * 128 + row) * NHALF + kseg * 64 + cc * 8,
                   Bs + chb * 8);
      }
      __syncthreads();                        // W1 ready

      // ---- GEMM1: h[16][128-chunk] = relu(xa @ W1 + b1)
      f32x4 acc1[2];
#pragma unroll
      for (int j = 0; j < 2; j++) acc1[j] = z;
#pragma unroll
      for (int kw = 0; kw < 4; kw++) {
        const int kseg = kw >> 1, g = (kw & 1) * 4 + q;
#pragma unroll
        for (int j = 0; j < 2; j++) {
          const int rb = wave * 32 + 16 * j + c;
          const bf16x8 bf = *(const bf16x8*)(Bs + (kseg * 128 + rb) * 64 + ((g ^ (rb & 7)) * 8));
          acc1[j] = __builtin_amdgcn_mfma_f32_16x16x32_bf16(af1[kw], bf, acc1[j], 0, 0, 0);
        }
      }
#pragma unroll
      for (int j = 0; j < 2; j++) {
        const int hc = wave * 32 + 16 * j + c;      // 0..127 within chunk
        const float bb = b1A[l * NHID + nc * 128 + hc];
#pragma unroll
        for (int r = 0; r < 4; r++) {
          float v = acc1[j][r] + bb;
          v = v > 0.f ? v : 0.f;
          Hs[swadr(hc >> 6, 16, 4 * q + r, hc & 63)] = f2bf(v);
        }
      }
      __syncthreads();                        // Hs ready; Bs free for W2

      // ---- stage W2I[0..256][nc*128 .. +128] as [kseg2][256][64] (64 KB)
#pragma unroll
      for (int u = 0; u < 16; u++) {
        const int chb = u * 256 + wave * 64;
        const int ch = chb + lane;
        const int kseg = ch >> 11, cs = ch & 2047;
        const int row = cs >> 3, cc = (cs & 7) ^ (row & 7);
        load_lds16(W2l + (size_t)row * NHID + nc * 128 + kseg * 64 + cc * 8,
                   Bs + chb * 8);
      }
      __syncthreads();                        // W2 ready

      // ---- GEMM2: K=128 of this chunk, accumulate over nc
#pragma unroll
      for (int kc = 0; kc < 4; kc++) {
        const int kch = kc * 4 + q;
        const int kseg = kch >> 3, g8 = kch & 7;
        const bf16x8 afh = *(const bf16x8*)(Hs + ((kch >> 3) * 16 + c) * 64 +
                                            (((kch & 7) ^ (c & 7)) * 8));
#pragma unroll
        for (int j = 0; j < 4; j++) {
          const int rb = wave * 64 + 16 * j + c;
          const bf16x8 bf = *(const bf16x8*)(Bs + (kseg * 256 + rb) * 64 + ((g8 ^ (rb & 7)) * 8));
          acc2[j] = __builtin_amdgcn_mfma_f32_16x16x32_bf16(afh, bf, acc2[j], 0, 0, 0);
        }
      }
      __syncthreads();                        // GEMM2 done; Bs free for next nc
    }

    // ---- coupling epilogue (even col=s, odd col=t)
    const int parity = c & 1;
    const int lastl = (l == NLAY - 1);
#pragma unroll
    for (int j = 0; j < 4; j++) {
      const int col = wave * 64 + 16 * j + c;
#pragma unroll
      for (int r = 0; r < 4; r++) {
        const float val = acc2[j][r];
        const float oth = __shfl_xor(val, 1);   // all lanes participate
        if (!parity) {
          const int feat = col >> 1;
          float sv = val + bsl[feat];
          if (!lastl) sv = fast_tanh(sv);
          const float t = oth + btl[feat];
          const int row = 4 * q + r;
          const int xaddr = swadr(feat >> 6, 16, row, feat & 63);
          const float xb = bf2f(XB[xaddr]);
          const float yb = xb * __expf(sv) + t;
          jr[r] += sv;
          XB[xaddr] = f2bf(yb);                 // in-place: same owner thread
          if (l >= 2) {
            const int k = lastl ? feat : (NHALF + feat);
            const size_t grow = (size_t)(m0 + row) * NF;
            xout[grow + k] = yb;
            xf8[(size_t)(m0 + row) * 256 + kperm(k)] = f2fp8(yb * SX);
          }
        }
      }
    }
  }

  // jac: reduce 16 c-lanes in-wave, then cross-wave via LDS (sum, not overwrite)
  float v0[4];
#pragma unroll
  for (int r = 0; r < 4; r++) {
    float v = jr[r];
    v += __shfl_xor(v, 1); v += __shfl_xor(v, 2);
    v += __shfl_xor(v, 4); v += __shfl_xor(v, 8);
    if (c == 0) {
      if (wave) jlds[wave - 1][4 * q + r] = v;
      else v0[r] = v;
    }
  }
  __syncthreads();
  if (wave == 0 && c == 0) {
#pragma unroll
    for (int r = 0; r < 4; r++) {
      const int row = 4 * q + r;
      jac[m0 + row] = v0[r] + jlds[0][row] + jlds[1][row] + jlds[2][row];
    }
  }
}

// ---------------------------------------------------------------- VQ argmax (fp8)
// Grid 1024 = 32 slices x 32 m-groups. XCD-aware: slice = (bx&7) + 8*(bx>>8)
// -> each XCD (bx%8) touches 4 slices x 256 KB = 1 MB P8, L2-resident
// (R8's bx&31 mapping thrashed L2: FETCH 830 MB). launch_bounds(256,3):
// VGPR cap 168 >= the 112 this kernel needs -> NO spill (R8's (256,4)
// cap=128 forced a 64-VGPR spill catastrophe, WRITE_SIZE 528 MB scratch),
// while actual 112 VGPR still permits 3-4 blocks/CU co-residency.
__global__ __launch_bounds__(256, 3)
void vq_argmax(const unsigned char* __restrict__ X8,   // [NB][256] permuted fp8
               const unsigned char* __restrict__ P8,   // [NK][256] permuted fp8
               const float* __restrict__ nbh,          // [NK] scaled 0.5||p||^2
               unsigned long long* __restrict__ gbest) // [NB] packed
{
  __shared__ __align__(16) unsigned char Bs[64 * 256];  // 16 KB
  const int tid = threadIdx.x;
  const int lane = tid & 63, wave = tid >> 6;
  const int y = (blockIdx.x & 7) + 8 * (blockIdx.x >> 8);   // slice 0..31
  const int m0 = ((blockIdx.x >> 3) & 31) * 256;            // m-group
  const int q = lane >> 4, c = lane & 15;
  const int mw = m0 + wave * 64;
  const int nbase = y * 1024;

  long af[4][8];
#pragma unroll
  for (int i = 0; i < 4; i++) {
    const unsigned char* xr = X8 + (size_t)(mw + 16 * i + c) * 256 + q * 64;
#pragma unroll
    for (int kc2 = 0; kc2 < 4; kc2++) {
      const i64x2 v = *(const i64x2*)(xr + kc2 * 16);
      af[i][2 * kc2] = v.x; af[i][2 * kc2 + 1] = v.y;
    }
  }

  float bestv[16];
  int besti[16];
#pragma unroll
  for (int t = 0; t < 16; t++) { bestv[t] = -1e30f; besti[t] = 0; }

  for (int nt = 0; nt < 16; nt++) {
    const int n0 = nbase + nt * 64;
    if (nt) __syncthreads();
    // stage 64 codes x 256 B: slot (row,gslot) holds src chunk gslot^(row&15)
#pragma unroll
    for (int u = 0; u < 4; u++) {
      const int chb = (u * 4 + wave) * 64;
      const int ch = chb + lane;
      const int row = ch >> 4, gslot = ch & 15;
      load_lds16(P8 + (size_t)(n0 + row) * 256 + (gslot ^ (row & 15)) * 16,
                 Bs + chb * 16);
    }
    __syncthreads();

    const f32x4 z = {0.f, 0.f, 0.f, 0.f};
    f32x4 acc[4][4];
#pragma unroll
    for (int i = 0; i < 4; i++)
#pragma unroll
      for (int j = 0; j < 4; j++) acc[i][j] = z;

#pragma unroll
    for (int kc2 = 0; kc2 < 4; kc2++) {
      const int g = q * 4 + kc2;
#pragma unroll
      for (int j = 0; j < 4; j++) {
        const int rb = 16 * j + c;
        const i64x2 b2 = *(const i64x2*)(Bs + rb * 256 + ((g ^ (rb & 15)) * 16));
#pragma unroll
        for (int i = 0; i < 4; i++) {
          acc[i][j] = __builtin_amdgcn_mfma_f32_16x16x32_fp8_fp8(af[i][2 * kc2],     b2.x, acc[i][j], 0, 0, 0);
          acc[i][j] = __builtin_amdgcn_mfma_f32_16x16x32_fp8_fp8(af[i][2 * kc2 + 1], b2.y, acc[i][j], 0, 0, 0);
        }
      }
    }

    // lane-local running argmax (ascending col + strict > = lowest-index ties)
#pragma unroll
    for (int j = 0; j < 4; j++) {
      const int col = n0 + 16 * j + c;
      const float nb = nbh[col];
#pragma unroll
      for (int i = 0; i < 4; i++)
#pragma unroll
        for (int r = 0; r < 4; r++) {
          const float sc = acc[i][j][r] - nb;
          const int t = i * 4 + r;
          if (sc > bestv[t]) { bestv[t] = sc; besti[t] = col; }
        }
    }
  }

  // reduce across 16 c-lanes per slot; rows unique per (wave, i, q, r)
#pragma unroll
  for (int t = 0; t < 16; t++) {
    float lv = bestv[t]; int li = besti[t];
#pragma unroll
    for (int mk = 8; mk >= 1; mk >>= 1) {
      const float ov = __shfl_xor(lv, mk);
      const int oi = __shfl_xor(li, mk);
      if (ov > lv || (ov == lv && oi < li)) { lv = ov; li = oi; }
    }
    if (c == 0) {
      const int row = mw + 16 * (t >> 2) + q * 4 + (t & 3);
      atomicMax(&gbest[row], packsi(lv, li));
    }
  }
}

// ---------------------------------------------------------------- fused prep
// bx [0,2048): prior -> permuted fp8 (scale SP) + scaled nbh | [2048,2112):
// W1 transpose | [2112,2240): Ws/Wt -> W2I interleave | [2240,2272): init
__global__ void prep_all(const float* __restrict__ W1,
                         const float* __restrict__ Ws,
                         const float* __restrict__ Wt,
                         const float* __restrict__ prior,
                         unsigned short* __restrict__ W1T,
                         unsigned short* __restrict__ W2I,
                         unsigned char* __restrict__ p8,
                         float* __restrict__ nbh,
                         unsigned long long* __restrict__ gbest,
                         float* __restrict__ accum)
{
  __shared__ float ts[64 * 65];
  const int bx = blockIdx.x;
  const int tid = threadIdx.x;
  if (bx < 2048) {
    const int k = bx * 16 + (tid >> 4);      // code index
    const int l16 = tid & 15;
    float s = 0.f;
#pragma unroll
    for (int v = 0; v < 4; v++) {
      const int off = (v * 16 + l16) * 4;    // k-offset, multiple of 4
      const float4 d = *(const float4*)(prior + (size_t)k * NF + off);
      uchar4 o;
      o.x = f2fp8(d.x * SP); o.y = f2fp8(d.y * SP);
      o.z = f2fp8(d.z * SP); o.w = f2fp8(d.w * SP);
      *(uchar4*)(p8 + (size_t)k * 256 + kperm(off)) = o;   // 4 consec bytes
      const float q0 = fp82f(o.x), q1 = fp82f(o.y), q2 = fp82f(o.z), q3 = fp82f(o.w);
      s += q0 * q0 + q1 * q1 + q2 * q2 + q3 * q3;
    }
#pragma unroll
    for (int mk = 8; mk >= 1; mk >>= 1) s += __shfl_xor(s, mk);
    if (l16 == 0) nbh[k] = 0.5f * s * (SX / SP);   // consistent scaled domain
  } else if (bx < 2112) {
    const int job = bx - 2048;
    const int l = job >> 4, t = job & 15;
    const int k0 = (t >> 3) * 64, n0 = (t & 7) * 64;
    const float* src = W1 + (size_t)l * NHALF * NHID;
#pragma unroll
    for (int v = 0; v < 16; v++) {
      const int e = tid + v * 256;
      const int kk = e >> 6, nn = e & 63;
      ts[kk * 65 + nn] = src[(size_t)(k0 + kk) * NHID + n0 + nn];
    }
    __syncthreads();
    unsigned short* dst = W1T + (size_t)l * NHID * NHALF;
#pragma unroll
    for (int v = 0; v < 16; v++) {
      const int e = tid + v * 256;
      const int nn = e >> 6, kk = e & 63;
      dst[(size_t)(n0 + nn) * NHALF + k0 + kk] = f2bf(ts[kk * 65 + nn]);
    }
  } else if (bx < 2240) {
    const int job = bx - 2112;
    const int l = job >> 5, rem = job & 31;
    const int b = rem >> 4;
    const int k0 = ((rem >> 1) & 7) * 64;
    const int f0 = (rem & 1) * 64;
    const float* src = (b ? Wt : Ws) + (size_t)l * NHID * NHALF;
#pragma unroll
    for (int v = 0; v < 16; v++) {
      const int e = tid + v * 256;
      const int kk = e >> 6, nn = e & 63;
      ts[kk * 65 + nn] = src[(size_t)(k0 + kk) * NHALF + f0 + nn];
    }
    __syncthreads();
#pragma unroll
    for (int v = 0; v < 16; v++) {
      const int e = tid + v * 256;
      const int nn = e >> 6, kk = e & 63;
      W2I[((size_t)l * NF + 2 * (f0 + nn) + b) * NHID + k0 + kk] = f2bf(ts[kk * 65 + nn]);
    }
  } else {
    const int idx = (bx - 2240) * 256 + tid;
    if (idx < NB) gbest[idx] = 0ull;
    if (idx < 4) accum[idx] = 0.f;             // [0] dist, [1] jac, [2] ticket
  }
}

// ---------------------------------------------------------------- VQ finalize (+fused loss)
__global__ void vq_finalize(const float* __restrict__ X,      // d_out x, fp32
                            const float* __restrict__ prior,
                            const unsigned long long* __restrict__ gbest,
                            const float* __restrict__ jac,
                            float* __restrict__ accum,        // [0]=dist,[1]=jac,[2]=ticket
                            float* __restrict__ loss)
{
  const int wave = threadIdx.x >> 6, lane = threadIdx.x & 63;
  const int gw = blockIdx.x * 4 + wave;        // 1024 waves, 8 rows each
  float accd = 0.f, accj = 0.f;
  for (int r = 0; r < 8; r++) {
    const int row = gw * 8 + r;
    const unsigned int idx = ~(unsigned int)(gbest[row]);   // low 32 bits = ~idx
    const float* x = X + (size_t)row * NF;
    const float* p = prior + (size_t)idx * NF;
#pragma unroll
    for (int u = 0; u < 4; u++) {
      const int d = lane + u * 64;
      const float df = x[d] - p[d];
      accd += df * df;
    }
    if (lane == 0) accj += jac[row];
  }
#pragma unroll
  for (int mk = 32; mk >= 1; mk >>= 1) {
    accd += __shfl_xor(accd, mk);
    accj += __shfl_xor(accj, mk);
  }
  __shared__ float sd[4], sj[4];
  if (lane == 0) { sd[wave] = accd; sj[wave] = accj; }
  __syncthreads();
  if (threadIdx.x == 0) {
    atomicAdd(&accum[0], sd[0] + sd[1] + sd[2] + sd[3]);
    atomicAdd(&accum[1], sj[0] + sj[1] + sj[2] + sj[3]);
    __threadfence();                           // adds visible device-wide
    const unsigned int tk = atomicAdd((unsigned int*)&accum[2], 1u);
    if (tk == 255u) {                          // last of 256 blocks
      __threadfence();
      const float d = atomicAdd(&accum[0], 0.f);   // coherent read
      const float j = atomicAdd(&accum[1], 0.f);
      loss[0] = 1.25f * (0.5f * d / (float)NB) - j / (float)NB;
    }
  }
}

// ---------------------------------------------------------------- launch
extern "C" void kernel_launch(void* const* d_in, const int* in_sizes, int n_in,
                              void* d_out, int out_size, void* d_ws, size_t ws_size,
                              hipStream_t stream)
{
  (void)in_sizes; (void)n_in; (void)out_size; (void)ws_size;
  const float* inputs = (const float*)d_in[0];
  const float* W1 = (const float*)d_in[1];
  const float* b1 = (const float*)d_in[2];
  const float* Ws = (const float*)d_in[3];
  const float* bs = (const float*)d_in[4];
  const float* Wt = (const float*)d_in[5];
  const float* bt = (const float*)d_in[6];
  const float* prior = (const float*)d_in[7];

  char* p = (char*)d_ws;
  auto alloc = [&](size_t bytes) { char* r = p; p += (bytes + 255) & ~(size_t)255; return r; };
  unsigned short* W1T  = (unsigned short*)alloc((size_t)NLAY * NHID * NHALF * 2);
  unsigned short* W2I  = (unsigned short*)alloc((size_t)NLAY * NF * NHID * 2);
  unsigned char* P8    = (unsigned char*)alloc((size_t)NK * 256);
  float* NBH           = (float*)alloc((size_t)NK * 4);
  unsigned char* XF8   = (unsigned char*)alloc((size_t)NB * 256);
  float* JAC           = (float*)alloc((size_t)NB * 4);
  unsigned long long* GBEST = (unsigned long long*)alloc((size_t)NB * 8);
  float* ACC           = (float*)alloc(256);

  float* xout = (float*)d_out;                 // [NB][NF]
  float* loss = xout + (size_t)NB * NF;        // scalar

  prep_all<<<dim3(2272), 256, 0, stream>>>(
      W1, Ws, Wt, prior, W1T, W2I, P8, NBH, GBEST, ACC);

  flow_all<<<dim3(NB / 16), 256, 0, stream>>>(
      inputs, W1T, W2I, b1, bs, bt, xout, XF8, JAC);

  vq_argmax<<<dim3(1024), 256, 0, stream>>>(XF8, P8, NBH, GBEST);
  vq_finalize<<<dim3(256), 256, 0, stream>>>(xout, prior, GBEST, JAC, ACC, loss);
}

// Round 10
// 315.259 us; speedup vs baseline: 2.0918x; 1.6160x over previous
//
#include <hip/hip_runtime.h>
#include <hip/hip_fp8.h>
#include <stdint.h>

// ---------------------------------------------------------------- constants
#define NB     8192     // batch
#define NF     256      // features
#define NHALF  128      // F/2
#define NHID   512      // hidden = 2F
#define NLAY   4        // coupling layers
#define NK     32768    // codebook size

#define SX     (1.0f / 16.0f)    // x scale for fp8 (|x|<=474/16=30 < 448)
#define SP     (256.0f)          // p scale for fp8 (Glorot +-0.0135*256=3.46)

typedef __attribute__((ext_vector_type(8))) short bf16x8;   // 8 bf16 = 4 VGPR
typedef __attribute__((ext_vector_type(4))) float f32x4;
typedef __attribute__((ext_vector_type(2))) long i64x2;     // 16 B = 2 fp8 frags

static __device__ __forceinline__ unsigned short f2bf(float f) {
  union { float f; unsigned int u; } v; v.f = f;
  return (unsigned short)((v.u + 0x7FFFu + ((v.u >> 16) & 1u)) >> 16);  // RNE
}
static __device__ __forceinline__ float bf2f(unsigned short u) {
  union { unsigned int u; float f; } v; v.u = ((unsigned int)u) << 16; return v.f;
}
static __device__ __forceinline__ unsigned char f2fp8(float f) {
  __hip_fp8_e4m3 q(f);                       // OCP e4m3fn, RNE + saturate
  return (unsigned char)q.__x;
}
static __device__ __forceinline__ float fp82f(unsigned char b) {
  __hip_fp8_e4m3 q; q.__x = b; return (float)q;
}
// permuted byte index inside a 256-k row: k' = q*64 + kc*8 + j for
// k = kc*32 + q*8 + j  -> one 16B load at q*64+kc2*16 = two K=32 fp8 frags
static __device__ __forceinline__ int kperm(int k) {
  return ((k >> 3) & 3) * 64 + ((k >> 5) << 3) + (k & 7);
}

// async global->LDS, 16B per lane; LDS dest = wave-uniform base + lane*16
static __device__ __forceinline__ void load_lds16(const void* g, void* l) {
  __builtin_amdgcn_global_load_lds(
      (const __attribute__((address_space(1))) unsigned int*)g,
      (__attribute__((address_space(3))) unsigned int*)l, 16, 0, 0);
}

// pack (score, idx) so u64 max == argmax with smallest-index tiebreak
static __device__ __forceinline__ unsigned long long packsi(float v, int idx) {
  unsigned int b = __float_as_uint(v);
  b = (b & 0x80000000u) ? ~b : (b | 0x80000000u);   // order-preserving map
  return ((unsigned long long)b << 32) | (unsigned int)(~(unsigned int)idx);
}

static __device__ __forceinline__ float fast_tanh(float x) {
  const float xc = fminf(fmaxf(x, -15.f), 15.f);
  const float e2 = __expf(2.f * xc);
  return 1.f - 2.f / (e2 + 1.f);
}

// LDS tile address: [kseg][row][64 shorts], 3-bit XOR chunk swizzle.
// Proven 0-conflict (R2/R4/R6) for ds_read_b128 with 16 lanes on rows.
static __device__ __forceinline__ int swadr(int kseg, int nrows, int row, int kin) {
  return (kseg * nrows + row) * 64 + (((kin >> 3) ^ (row & 7)) * 8) + (kin & 7);
}

// ---------------------------------------------------------------- fused flow (ALL 4 layers)
// NO weight staging: B-fragments are read as PLAIN global loads into VGPRs
// (weights are 1.5 MB, read by all 512 blocks -> L1/L2-hot). This removes the
// global_load_lds+barrier structure that pinned flow at ~130-160 us across
// R4/R6/R7/R9 (every barrier drains the DMA queue; DMA LDS-writes contend
// with compute ds_reads - R5 evidence). Only Xb/Hs live in LDS; 9 barriers
// per layer with no VMEM-to-LDS traffic behind them.
// One block = 16 rows, 4 waves column-split, grid 512 -> 8 waves/CU.
__global__ __launch_bounds__(256, 2)
void flow_all(const float* __restrict__ in,
              const unsigned short* __restrict__ W1T,   // [L][512 col][128 k]
              const unsigned short* __restrict__ W2I,   // [L][256 col][512 k] s/t interleaved
              const float* __restrict__ b1A,
              const float* __restrict__ bsA,
              const float* __restrict__ btA,
              float* __restrict__ xout,
              unsigned char* __restrict__ xf8,          // [NB][256] permuted fp8(x*SX)
              float* __restrict__ jac)
{
  __shared__ __align__(16) unsigned short Xb[2][16 * 128];   // 8 KB x-state
  __shared__ __align__(16) unsigned short Hs[2 * 16 * 64];   // 4 KB h chunk
  __shared__ float jlds[3][16];
  const int tid = threadIdx.x;
  const int lane = tid & 63, wave = tid >> 6;
  const int q = lane >> 4, c = lane & 15;
  const int m0 = blockIdx.x * 16;

  // ---- init x-state: Xb[0]=bf16(in[:, :128]) (xa0), Xb[1]=bf16(in[:,128:]) (xb0)
#pragma unroll
  for (int v = 0; v < 4; v++) {
    const int t4 = tid + v * 256;            // 1024 float4s = 16 rows x 64
    const int row = t4 >> 6, f4 = t4 & 63;
    const float4 d = *(const float4*)(in + (size_t)(m0 + row) * NF + f4 * 4);
    unsigned short* dst = Xb[f4 >> 5];
    const int feat = (f4 & 31) * 4;
    const float vals[4] = {d.x, d.y, d.z, d.w};
#pragma unroll
    for (int u = 0; u < 4; u++) {
      const int fe = feat + u;
      dst[swadr(fe >> 6, 16, row, fe & 63)] = f2bf(vals[u]);
    }
  }

  float jr[4] = {0.f, 0.f, 0.f, 0.f};
  const f32x4 z = {0.f, 0.f, 0.f, 0.f};

  for (int l = 0; l < NLAY; l++) {
    __syncthreads();                          // x-state settled (LDS only)
    const unsigned short* W1l = W1T + (size_t)l * NHID * NHALF;
    const unsigned short* W2l = W2I + (size_t)l * NF * NHID;
    const float* bsl = bsA + l * NHALF;
    const float* btl = btA + l * NHALF;
    unsigned short* XA = Xb[l & 1];
    unsigned short* XB = Xb[1 - (l & 1)];

    // GEMM1 A-fragments from XA (row = c, k-chunk = kw*4+q)
    bf16x8 af1[4];
#pragma unroll
    for (int kw = 0; kw < 4; kw++) {
      const int kch = kw * 4 + q;
      af1[kw] = *(const bf16x8*)(XA + ((kch >> 3) * 16 + c) * 64 +
                                 (((kch & 7) ^ (c & 7)) * 8));
    }

    f32x4 acc2[4];
#pragma unroll
    for (int j = 0; j < 4; j++) acc2[j] = z;

    for (int nc = 0; nc < 4; nc++) {
      // ---- GEMM1: this wave's 32 h-cols of the 128-col chunk, K=128
      f32x4 acc1[2];
#pragma unroll
      for (int j = 0; j < 2; j++) acc1[j] = z;
#pragma unroll
      for (int j = 0; j < 2; j++) {
        const int col = nc * 128 + wave * 32 + 16 * j + c;
        const unsigned short* wrow = W1l + (size_t)col * NHALF + q * 8;
#pragma unroll
        for (int kw = 0; kw < 4; kw++) {
          const bf16x8 bf = *(const bf16x8*)(wrow + kw * 32);
          acc1[j] = __builtin_amdgcn_mfma_f32_16x16x32_bf16(af1[kw], bf, acc1[j], 0, 0, 0);
        }
      }
#pragma unroll
      for (int j = 0; j < 2; j++) {
        const int hc = wave * 32 + 16 * j + c;      // 0..127 within chunk
        const float bb = b1A[l * NHID + nc * 128 + hc];
#pragma unroll
        for (int r = 0; r < 4; r++) {
          float v = acc1[j][r] + bb;
          v = v > 0.f ? v : 0.f;
          Hs[swadr(hc >> 6, 16, 4 * q + r, hc & 63)] = f2bf(v);
        }
      }
      __syncthreads();                        // Hs ready (lgkmcnt only)

      // ---- GEMM2: K=128 of this chunk; W2 frags straight from global
#pragma unroll
      for (int kc = 0; kc < 4; kc++) {
        const int kch = kc * 4 + q;
        const bf16x8 afh = *(const bf16x8*)(Hs + ((kch >> 3) * 16 + c) * 64 +
                                            (((kch & 7) ^ (c & 7)) * 8));
#pragma unroll
        for (int j = 0; j < 4; j++) {
          const int col = wave * 64 + 16 * j + c;
          const bf16x8 bf = *(const bf16x8*)(W2l + (size_t)col * NHID +
                                             nc * 128 + kc * 32 + q * 8);
          acc2[j] = __builtin_amdgcn_mfma_f32_16x16x32_bf16(afh, bf, acc2[j], 0, 0, 0);
        }
      }
      __syncthreads();                        // Hs consumed; free for next nc
    }

    // ---- coupling epilogue (even col=s, odd col=t)
    const int parity = c & 1;
    const int lastl = (l == NLAY - 1);
#pragma unroll
    for (int j = 0; j < 4; j++) {
      const int col = wave * 64 + 16 * j + c;
#pragma unroll
      for (int r = 0; r < 4; r++) {
        const float val = acc2[j][r];
        const float oth = __shfl_xor(val, 1);   // all lanes participate
        if (!parity) {
          const int feat = col >> 1;
          float sv = val + bsl[feat];
          if (!lastl) sv = fast_tanh(sv);
          const float t = oth + btl[feat];
          const int row = 4 * q + r;
          const int xaddr = swadr(feat >> 6, 16, row, feat & 63);
          const float xb = bf2f(XB[xaddr]);
          const float yb = xb * __expf(sv) + t;
          jr[r] += sv;
          XB[xaddr] = f2bf(yb);                 // in-place: same owner thread
          if (l >= 2) {
            const int k = lastl ? feat : (NHALF + feat);
            const size_t grow = (size_t)(m0 + row) * NF;
            xout[grow + k] = yb;
            xf8[(size_t)(m0 + row) * 256 + kperm(k)] = f2fp8(yb * SX);
          }
        }
      }
    }
  }

  // jac: reduce 16 c-lanes in-wave, then cross-wave via LDS (sum, not overwrite)
  float v0[4];
#pragma unroll
  for (int r = 0; r < 4; r++) {
    float v = jr[r];
    v += __shfl_xor(v, 1); v += __shfl_xor(v, 2);
    v += __shfl_xor(v, 4); v += __shfl_xor(v, 8);
    if (c == 0) {
      if (wave) jlds[wave - 1][4 * q + r] = v;
      else v0[r] = v;
    }
  }
  __syncthreads();
  if (wave == 0 && c == 0) {
#pragma unroll
    for (int r = 0; r < 4; r++) {
      const int row = 4 * q + r;
      jac[m0 + row] = v0[r] + jlds[0][row] + jlds[1][row] + jlds[2][row];
    }
  }
}

// ---------------------------------------------------------------- VQ argmax (fp8)
// EXACT R7 configuration (measured 113 us, VGPR 112, no spill): grid 512,
// slice = bx & 15 (2 slices x 512 KB per XCD -> L2-resident, FETCH 12 MB),
// launch_bounds(256,2) -- empirical VGPR cap on this toolchain is 256/w,
// so w=2 -> 128 >= 112 (R8's w=4 -> cap 64 and R9's w=3 -> cap 84 both
// forced catastrophic scratch spills: WRITE_SIZE 528-574 MB).
__global__ __launch_bounds__(256, 2)
void vq_argmax(const unsigned char* __restrict__ X8,   // [NB][256] permuted fp8
               const unsigned char* __restrict__ P8,   // [NK][256] permuted fp8
               const float* __restrict__ nbh,          // [NK] scaled 0.5||p||^2
               unsigned long long* __restrict__ gbest) // [NB] packed
{
  __shared__ __align__(16) unsigned char Bs[64 * 256];  // 16 KB
  const int tid = threadIdx.x;
  const int lane = tid & 63, wave = tid >> 6;
  const int y = blockIdx.x & 15;
  const int m0 = (blockIdx.x >> 4) * 256;
  const int q = lane >> 4, c = lane & 15;
  const int mw = m0 + wave * 64;

  long af[4][8];
#pragma unroll
  for (int i = 0; i < 4; i++) {
    const unsigned char* xr = X8 + (size_t)(mw + 16 * i + c) * 256 + q * 64;
#pragma unroll
    for (int kc2 = 0; kc2 < 4; kc2++) {
      const i64x2 v = *(const i64x2*)(xr + kc2 * 16);
      af[i][2 * kc2] = v.x; af[i][2 * kc2 + 1] = v.y;
    }
  }

  float bestv[16];
  int besti[16];
#pragma unroll
  for (int t = 0; t < 16; t++) { bestv[t] = -1e30f; besti[t] = 0; }

  for (int nt = 0; nt < 32; nt++) {
    const int n0 = y * 2048 + nt * 64;
    if (nt) __syncthreads();
    // stage 64 codes x 256 B: slot (row,gslot) holds src chunk gslot^(row&15)
#pragma unroll
    for (int u = 0; u < 4; u++) {
      const int chb = (u * 4 + wave) * 64;
      const int ch = chb + lane;
      const int row = ch >> 4, gslot = ch & 15;
      load_lds16(P8 + (size_t)(n0 + row) * 256 + (gslot ^ (row & 15)) * 16,
                 Bs + chb * 16);
    }
    __syncthreads();

    const f32x4 z = {0.f, 0.f, 0.f, 0.f};
    f32x4 acc[4][4];
#pragma unroll
    for (int i = 0; i < 4; i++)
#pragma unroll
      for (int j = 0; j < 4; j++) acc[i][j] = z;

#pragma unroll
    for (int kc2 = 0; kc2 < 4; kc2++) {
      const int g = q * 4 + kc2;
#pragma unroll
      for (int j = 0; j < 4; j++) {
        const int rb = 16 * j + c;
        const i64x2 b2 = *(const i64x2*)(Bs + rb * 256 + ((g ^ (rb & 15)) * 16));
#pragma unroll
        for (int i = 0; i < 4; i++) {
          acc[i][j] = __builtin_amdgcn_mfma_f32_16x16x32_fp8_fp8(af[i][2 * kc2],     b2.x, acc[i][j], 0, 0, 0);
          acc[i][j] = __builtin_amdgcn_mfma_f32_16x16x32_fp8_fp8(af[i][2 * kc2 + 1], b2.y, acc[i][j], 0, 0, 0);
        }
      }
    }

    // lane-local running argmax (ascending col + strict > = lowest-index ties)
#pragma unroll
    for (int j = 0; j < 4; j++) {
      const int col = n0 + 16 * j + c;
      const float nb = nbh[col];
#pragma unroll
      for (int i = 0; i < 4; i++)
#pragma unroll
        for (int r = 0; r < 4; r++) {
          const float sc = acc[i][j][r] - nb;
          const int t = i * 4 + r;
          if (sc > bestv[t]) { bestv[t] = sc; besti[t] = col; }
        }
    }
  }

  // reduce across 16 c-lanes per slot; rows unique per (wave, i, q, r)
#pragma unroll
  for (int t = 0; t < 16; t++) {
    float lv = bestv[t]; int li = besti[t];
#pragma unroll
    for (int mk = 8; mk >= 1; mk >>= 1) {
      const float ov = __shfl_xor(lv, mk);
      const int oi = __shfl_xor(li, mk);
      if (ov > lv || (ov == lv && oi < li)) { lv = ov; li = oi; }
    }
    if (c == 0) {
      const int row = mw + 16 * (t >> 2) + q * 4 + (t & 3);
      atomicMax(&gbest[row], packsi(lv, li));
    }
  }
}

// ---------------------------------------------------------------- fused prep
// bx [0,2048): prior -> permuted fp8 (scale SP) + scaled nbh | [2048,2112):
// W1 transpose | [2112,2240): Ws/Wt -> W2I interleave | [2240,2272): init
__global__ void prep_all(const float* __restrict__ W1,
                         const float* __restrict__ Ws,
                         const float* __restrict__ Wt,
                         const float* __restrict__ prior,
                         unsigned short* __restrict__ W1T,
                         unsigned short* __restrict__ W2I,
                         unsigned char* __restrict__ p8,
                         float* __restrict__ nbh,
                         unsigned long long* __restrict__ gbest,
                         float* __restrict__ accum)
{
  __shared__ float ts[64 * 65];
  const int bx = blockIdx.x;
  const int tid = threadIdx.x;
  if (bx < 2048) {
    const int k = bx * 16 + (tid >> 4);      // code index
    const int l16 = tid & 15;
    float s = 0.f;
#pragma unroll
    for (int v = 0; v < 4; v++) {
      const int off = (v * 16 + l16) * 4;    // k-offset, multiple of 4
      const float4 d = *(const float4*)(prior + (size_t)k * NF + off);
      uchar4 o;
      o.x = f2fp8(d.x * SP); o.y = f2fp8(d.y * SP);
      o.z = f2fp8(d.z * SP); o.w = f2fp8(d.w * SP);
      *(uchar4*)(p8 + (size_t)k * 256 + kperm(off)) = o;   // 4 consec bytes
      const float q0 = fp82f(o.x), q1 = fp82f(o.y), q2 = fp82f(o.z), q3 = fp82f(o.w);
      s += q0 * q0 + q1 * q1 + q2 * q2 + q3 * q3;
    }
#pragma unroll
    for (int mk = 8; mk >= 1; mk >>= 1) s += __shfl_xor(s, mk);
    if (l16 == 0) nbh[k] = 0.5f * s * (SX / SP);   // consistent scaled domain
  } else if (bx < 2112) {
    const int job = bx - 2048;
    const int l = job >> 4, t = job & 15;
    const int k0 = (t >> 3) * 64, n0 = (t & 7) * 64;
    const float* src = W1 + (size_t)l * NHALF * NHID;
#pragma unroll
    for (int v = 0; v < 16; v++) {
      const int e = tid + v * 256;
      const int kk = e >> 6, nn = e & 63;
      ts[kk * 65 + nn] = src[(size_t)(k0 + kk) * NHID + n0 + nn];
    }
    __syncthreads();
    unsigned short* dst = W1T + (size_t)l * NHID * NHALF;
#pragma unroll
    for (int v = 0; v < 16; v++) {
      const int e = tid + v * 256;
      const int nn = e >> 6, kk = e & 63;
      dst[(size_t)(n0 + nn) * NHALF + k0 + kk] = f2bf(ts[kk * 65 + nn]);
    }
  } else if (bx < 2240) {
    const int job = bx - 2112;
    const int l = job >> 5, rem = job & 31;
    const int b = rem >> 4;
    const int k0 = ((rem >> 1) & 7) * 64;
    const int f0 = (rem & 1) * 64;
    const float* src = (b ? Wt : Ws) + (size_t)l * NHID * NHALF;
#pragma unroll
    for (int v = 0; v < 16; v++) {
      const int e = tid + v * 256;
      const int kk = e >> 6, nn = e & 63;
      ts[kk * 65 + nn] = src[(size_t)(k0 + kk) * NHALF + f0 + nn];
    }
    __syncthreads();
#pragma unroll
    for (int v = 0; v < 16; v++) {
      const int e = tid + v * 256;
      const int nn = e >> 6, kk = e & 63;
      W2I[((size_t)l * NF + 2 * (f0 + nn) + b) * NHID + k0 + kk] = f2bf(ts[kk * 65 + nn]);
    }
  } else {
    const int idx = (bx - 2240) * 256 + tid;
    if (idx < NB) gbest[idx] = 0ull;
    if (idx < 4) accum[idx] = 0.f;             // [0] dist, [1] jac, [2] ticket
  }
}

// ---------------------------------------------------------------- VQ finalize (+fused loss)
__global__ void vq_finalize(const float* __restrict__ X,      // d_out x, fp32
                            const float* __restrict__ prior,
                            const unsigned long long* __restrict__ gbest,
                            const float* __restrict__ jac,
                            float* __restrict__ accum,        // [0]=dist,[1]=jac,[2]=ticket
                            float* __restrict__ loss)
{
  const int wave = threadIdx.x >> 6, lane = threadIdx.x & 63;
  const int gw = blockIdx.x * 4 + wave;        // 1024 waves, 8 rows each
  float accd = 0.f, accj = 0.f;
  for (int r = 0; r < 8; r++) {
    const int row = gw * 8 + r;
    const unsigned int idx = ~(unsigned int)(gbest[row]);   // low 32 bits = ~idx
    const float* x = X + (size_t)row * NF;
    const float* p = prior + (size_t)idx * NF;
#pragma unroll
    for (int u = 0; u < 4; u++) {
      const int d = lane + u * 64;
      const float df = x[d] - p[d];
      accd += df * df;
    }
    if (lane == 0) accj += jac[row];
  }
#pragma unroll
  for (int mk = 32; mk >= 1; mk >>= 1) {
    accd += __shfl_xor(accd, mk);
    accj += __shfl_xor(accj, mk);
  }
  __shared__ float sd[4], sj[4];
  if (lane == 0) { sd[wave] = accd; sj[wave] = accj; }
  __syncthreads();
  if (threadIdx.x == 0) {
    atomicAdd(&accum[0], sd[0] + sd[1] + sd[2] + sd[3]);
    atomicAdd(&accum[1], sj[0] + sj[1] + sj[2] + sj[3]);
    __threadfence();                           // adds visible device-wide
    const unsigned int tk = atomicAdd((unsigned int*)&accum[2], 1u);
    if (tk == 255u) {                          // last of 256 blocks
      __threadfence();
      const float d = atomicAdd(&accum[0], 0.f);   // coherent read
      const float j = atomicAdd(&accum[1], 0.f);
      loss[0] = 1.25f * (0.5f * d / (float)NB) - j / (float)NB;
    }
  }
}

// ---------------------------------------------------------------- launch
extern "C" void kernel_launch(void* const* d_in, const int* in_sizes, int n_in,
                              void* d_out, int out_size, void* d_ws, size_t ws_size,
                              hipStream_t stream)
{
  (void)in_sizes; (void)n_in; (void)out_size; (void)ws_size;
  const float* inputs = (const float*)d_in[0];
  const float* W1 = (const float*)d_in[1];
  const float* b1 = (const float*)d_in[2];
  const float* Ws = (const float*)d_in[3];
  const float* bs = (const float*)d_in[4];
  const float* Wt = (const float*)d_in[5];
  const float* bt = (const float*)d_in[6];
  const float* prior = (const float*)d_in[7];

  char* p = (char*)d_ws;
  auto alloc = [&](size_t bytes) { char* r = p; p += (bytes + 255) & ~(size_t)255; return r; };
  unsigned short* W1T  = (unsigned short*)alloc((size_t)NLAY * NHID * NHALF * 2);
  unsigned short* W2I  = (unsigned short*)alloc((size_t)NLAY * NF * NHID * 2);
  unsigned char* P8    = (unsigned char*)alloc((size_t)NK * 256);
  float* NBH           = (float*)alloc((size_t)NK * 4);
  unsigned char* XF8   = (unsigned char*)alloc((size_t)NB * 256);
  float* JAC           = (float*)alloc((size_t)NB * 4);
  unsigned long long* GBEST = (unsigned long long*)alloc((size_t)NB * 8);
  float* ACC           = (float*)alloc(256);

  float* xout = (float*)d_out;                 // [NB][NF]
  float* loss = xout + (size_t)NB * NF;        // scalar

  prep_all<<<dim3(2272), 256, 0, stream>>>(
      W1, Ws, Wt, prior, W1T, W2I, P8, NBH, GBEST, ACC);

  flow_all<<<dim3(NB / 16), 256, 0, stream>>>(
      inputs, W1T, W2I, b1, bs, bt, xout, XF8, JAC);

  vq_argmax<<<dim3(32 * 16), 256, 0, stream>>>(XF8, P8, NBH, GBEST);
  vq_finalize<<<dim3(256), 256, 0, stream>>>(xout, prior, GBEST, JAC, ACC, loss);
}